// Round 1
// 1727.899 us; speedup vs baseline: 1.8682x; 1.8682x over previous
//
#include <hip/hip_runtime.h>
#include <cstdint>

#define M_ROWS 4096
#define K_DIM  768
#define N_HID  24576
#define TOPK   32
#define MAXCAND 64
#define KC     2304   // 3*768: split-K concat [Ah|Ah|Al] x [Wh|Wl|Wh]

typedef float f32x4 __attribute__((ext_vector_type(4)));
typedef short s16x8 __attribute__((ext_vector_type(8)));

// ---------------------------------------------------------------------------
// bf16 split helpers (hand-rolled RNE; no NaN/Inf in this data)
// ---------------------------------------------------------------------------
__device__ __forceinline__ unsigned short f2bf_rne(float f) {
    uint32_t u = __float_as_uint(f);
    uint32_t r = (u + 0x7fffu + ((u >> 16) & 1u)) >> 16;
    return (unsigned short)r;
}
__device__ __forceinline__ float bf2f(unsigned short h) {
    return __uint_as_float((uint32_t)h << 16);
}

// global -> LDS async copy, 16B per lane, wave-uniform LDS base
#define GLOAD(g, l) __builtin_amdgcn_global_load_lds( \
    (const __attribute__((address_space(1))) uint32_t*)(g), \
    (__attribute__((address_space(3))) uint32_t*)(l), 16, 0, 0)

// ---------------------------------------------------------------------------
// Kernel 0a: Acat[m, 0:768]=hi(A-b), [768:1536]=hi, [1536:2304]=lo
// ---------------------------------------------------------------------------
__global__ __launch_bounds__(256) void convert_a(
    const float* __restrict__ A, const float* __restrict__ b_pre,
    unsigned short* __restrict__ Acat)
{
    const int idx = blockIdx.x * 256 + threadIdx.x;    // over M*K/4
    const int m  = idx / (K_DIM / 4);
    const int k  = (idx % (K_DIM / 4)) * 4;
    const float4 a4 = *(const float4*)(A + (size_t)m * K_DIM + k);
    const float4 b4 = *(const float4*)(b_pre + k);
    const float av[4] = {a4.x - b4.x, a4.y - b4.y, a4.z - b4.z, a4.w - b4.w};
    unsigned short hi[4], lo[4];
    #pragma unroll
    for (int i = 0; i < 4; ++i) {
        hi[i] = f2bf_rne(av[i]);
        lo[i] = f2bf_rne(av[i] - bf2f(hi[i]));
    }
    unsigned short* row = Acat + (size_t)m * KC + k;
    *(ushort4*)(row)        = make_ushort4(hi[0], hi[1], hi[2], hi[3]);
    *(ushort4*)(row + 768)  = make_ushort4(hi[0], hi[1], hi[2], hi[3]);
    *(ushort4*)(row + 1536) = make_ushort4(lo[0], lo[1], lo[2], lo[3]);
}

// ---------------------------------------------------------------------------
// Kernel 0b: WT[n, 0:768]=hi(W[:,n]), [768:1536]=lo, [1536:2304]=hi  (B^T)
// 64x64 tiles via LDS transpose.
// ---------------------------------------------------------------------------
__global__ __launch_bounds__(256) void convert_w(
    const float* __restrict__ W, unsigned short* __restrict__ WT)
{
    __shared__ float tile[64][65];
    const int tid = threadIdx.x;
    const int n0 = blockIdx.x * 64;
    const int k0 = blockIdx.y * 64;

    #pragma unroll
    for (int i = 0; i < 16; ++i) {
        int e = i * 256 + tid;
        int r = e >> 6, c = e & 63;          // r: k-row, c: n-col
        tile[r][c] = W[(size_t)(k0 + r) * N_HID + n0 + c];
    }
    __syncthreads();
    #pragma unroll
    for (int i = 0; i < 8; ++i) {
        int p = i * 256 + tid;               // 0..2047
        int n = p >> 5;                      // 0..63
        int k2 = (p & 31) * 2;               // 0..62 step 2
        float v0 = tile[k2][n], v1 = tile[k2 + 1][n];
        unsigned short h0 = f2bf_rne(v0), h1 = f2bf_rne(v1);
        unsigned short l0 = f2bf_rne(v0 - bf2f(h0)), l1 = f2bf_rne(v1 - bf2f(h1));
        unsigned short* row = WT + (size_t)(n0 + n) * KC + k0 + k2;
        *(ushort2*)(row)        = make_ushort2(h0, h1);
        *(ushort2*)(row + 768)  = make_ushort2(l0, l1);
        *(ushort2*)(row + 1536) = make_ushort2(h0, h1);
    }
}

// ---------------------------------------------------------------------------
// Kernel 1: acts = Acat @ WT^T   (bf16 MFMA, fp32 accumulate)
// 128x128 tile, BK=32, 4 waves x (64x64), 4x4 frags of 16x16x32. m97 structure.
// ---------------------------------------------------------------------------
__global__ __launch_bounds__(256) void encode_mfma(
    const unsigned short* __restrict__ Acat, const unsigned short* __restrict__ WT,
    float* __restrict__ acts)
{
    __shared__ unsigned short As[128 * 32];
    __shared__ unsigned short Bs[128 * 32];

    const int tid  = threadIdx.x;
    const int lane = tid & 63;
    const int wave = tid >> 6;
    const int wr = wave >> 1;                  // 0..1: wave row
    const int wc = wave & 1;                   // 0..1: wave col
    const int m0 = blockIdx.y * 128;
    const int n0 = blockIdx.x * 128;

    f32x4 acc[4][4] = {};

    // staging: tile = 8KB = 8 chunks of 1024B; wave w owns chunks {2w, 2w+1}.
    // chunk c, lane l -> LDS byte c*1024 + l*16 -> row c*16 + l/4, kelem (l&3)*8
    const int c0   = wave * 2;
    const int row0 = c0 * 16 + (lane >> 2);
    const int kel  = (lane & 3) * 8;
    const unsigned short* aSrc0 = Acat + (size_t)(m0 + row0) * KC + kel;
    const unsigned short* aSrc1 = aSrc0 + (size_t)16 * KC;
    const unsigned short* bSrc0 = WT   + (size_t)(n0 + row0) * KC + kel;
    const unsigned short* bSrc1 = bSrc0 + (size_t)16 * KC;
    unsigned short* aDst0 = As + c0 * 512;
    unsigned short* aDst1 = As + (c0 + 1) * 512;
    unsigned short* bDst0 = Bs + c0 * 512;
    unsigned short* bDst1 = Bs + (c0 + 1) * 512;

    // fragment read offsets (linear LDS [row][32])
    const int aoff = (wr * 64 + (lane & 15)) * 32 + (lane >> 4) * 8;
    const int boff = (wc * 64 + (lane & 15)) * 32 + (lane >> 4) * 8;

    for (int k0 = 0; k0 < KC; k0 += 32) {
        GLOAD(aSrc0 + k0, aDst0);
        GLOAD(aSrc1 + k0, aDst1);
        GLOAD(bSrc0 + k0, bDst0);
        GLOAD(bSrc1 + k0, bDst1);
        __syncthreads();   // drains vmcnt before barrier

        s16x8 a[4], b[4];
        #pragma unroll
        for (int i = 0; i < 4; ++i)
            a[i] = *(const s16x8*)(As + aoff + i * 16 * 32);
        #pragma unroll
        for (int j = 0; j < 4; ++j)
            b[j] = *(const s16x8*)(Bs + boff + j * 16 * 32);
        #pragma unroll
        for (int i = 0; i < 4; ++i)
            #pragma unroll
            for (int j = 0; j < 4; ++j)
                asm("v_mfma_f32_16x16x32_bf16 %0, %1, %2, %0"
                    : "+v"(acc[i][j]) : "v"(a[i]), "v"(b[j]));
        __syncthreads();   // all reads done before next stage overwrites
    }

    // epilogue: C/D layout col=lane&15, row=(lane>>4)*4+reg  [m89-verified]
    const int crow = (lane >> 4) * 4;
    const int ccol = lane & 15;
    #pragma unroll
    for (int i = 0; i < 4; ++i) {
        #pragma unroll
        for (int r = 0; r < 4; ++r) {
            float* dst = acts + (size_t)(m0 + wr * 64 + i * 16 + crow + r) * N_HID
                       + n0 + wc * 64 + ccol;
            #pragma unroll
            for (int j = 0; j < 4; ++j)
                dst[j * 16] = acc[i][j][r];
        }
    }
}

// ---------------------------------------------------------------------------
// Kernel 2: per-row top-32 with fp64 boundary repair, z scatter, fused decode.
// (unchanged from previous round)
// ---------------------------------------------------------------------------
__device__ __forceinline__ uint32_t f2k(float f) {
    uint32_t b = __float_as_uint(f);
    return (b & 0x80000000u) ? ~b : (b | 0x80000000u);
}
__device__ __forceinline__ float k2f(uint32_t k) {
    return __uint_as_float((k & 0x80000000u) ? (k ^ 0x80000000u) : ~k);
}

__global__ __launch_bounds__(256) void topk_decode(
    const float* __restrict__ acts, const float* __restrict__ A,
    const float* __restrict__ W_dec, const float* __restrict__ b_pre,
    float* __restrict__ z, float* __restrict__ recon)
{
    const int row = blockIdx.x;
    const int tid = threadIdx.x;
    const float* arow = acts + (size_t)row * N_HID;

    __shared__ float    ash[K_DIM];
    __shared__ uint32_t hist[256];
    __shared__ uint32_t sfx[256];
    __shared__ uint32_t bsel, bgt;
    __shared__ int      candN;
    __shared__ int      candIdx[MAXCAND];
    __shared__ double   candVal[MAXCAND];
    __shared__ double   partsum[4][MAXCAND];
    __shared__ int      selIdx[TOPK];
    __shared__ float    selVal[TOPK];

    for (int i = tid; i < K_DIM; i += 256) ash[i] = A[(size_t)row * K_DIM + i] - b_pre[i];

    uint32_t key[96];
    #pragma unroll
    for (int i = 0; i < 24; ++i) {
        const float4 v = *(const float4*)(arow + ((size_t)(tid + i * 256) << 2));
        key[i * 4 + 0] = f2k(v.x);
        key[i * 4 + 1] = f2k(v.y);
        key[i * 4 + 2] = f2k(v.z);
        key[i * 4 + 3] = f2k(v.w);
    }

    uint32_t prefix = 0;
    uint32_t kneed = TOPK;
    for (int shift = 24; shift >= 0; shift -= 8) {
        hist[tid] = 0u;
        __syncthreads();
        #pragma unroll
        for (int i = 0; i < 96; ++i) {
            uint32_t kk = key[i];
            bool m = (shift == 24) || ((kk >> (shift + 8)) == prefix);
            if (m) atomicAdd(&hist[(kk >> shift) & 255u], 1u);
        }
        __syncthreads();
        sfx[tid] = hist[tid];
        __syncthreads();
        for (int off = 1; off < 256; off <<= 1) {
            uint32_t t = (tid + off < 256) ? sfx[tid + off] : 0u;
            __syncthreads();
            sfx[tid] += t;
            __syncthreads();
        }
        uint32_t ge = sfx[tid];
        uint32_t gt = (tid < 255) ? sfx[tid + 1] : 0u;
        if (gt < kneed && kneed <= ge) { bsel = (uint32_t)tid; bgt = gt; }
        __syncthreads();
        prefix = (prefix << 8) | bsel;
        kneed -= bgt;
        __syncthreads();
    }
    const float vT = k2f(prefix);
    const uint32_t keyLo = f2k(vT - 1e-3f);

    if (tid == 0) candN = 0;
    __syncthreads();
    #pragma unroll
    for (int i = 0; i < 24; ++i) {
        #pragma unroll
        for (int j = 0; j < 4; ++j) {
            if (key[i * 4 + j] >= keyLo) {
                int s = atomicAdd(&candN, 1);
                if (s < MAXCAND) candIdx[s] = (tid + i * 256) * 4 + j;
            }
        }
    }
    __syncthreads();
    const int nc = candN < MAXCAND ? candN : MAXCAND;

    {
        const int c = tid & 63, part = tid >> 6;
        double s = 0.0;
        if (c < nc) {
            const float* wr = W_dec + (size_t)candIdx[c] * K_DIM + part * 192;
            const float* ar = ash + part * 192;
            #pragma unroll 4
            for (int d = 0; d < 192; ++d) s += (double)ar[d] * (double)wr[d];
        }
        partsum[part][c] = s;
    }
    __syncthreads();
    if (tid < MAXCAND)
        candVal[tid] = partsum[0][tid] + partsum[1][tid] + partsum[2][tid] + partsum[3][tid];
    __syncthreads();

    if (tid < nc) {
        const double v = candVal[tid];
        const int    idx = candIdx[tid];
        int rank = 0;
        for (int t = 0; t < nc; ++t) {
            double vt2 = candVal[t]; int it = candIdx[t];
            if (vt2 > v || (vt2 == v && it < idx)) rank++;
        }
        if (rank < TOPK) { selIdx[rank] = idx; selVal[rank] = (float)v; }
    }
    __syncthreads();

    float* zrow = z + (size_t)row * N_HID;
    const float4 zero4 = make_float4(0.f, 0.f, 0.f, 0.f);
    #pragma unroll
    for (int i = 0; i < 24; ++i)
        *(float4*)(zrow + ((size_t)(tid + i * 256) << 2)) = zero4;
    __syncthreads();
    if (tid < TOPK) zrow[selIdx[tid]] = selVal[tid];

    const int d0 = tid;
    float a0 = b_pre[d0], a1 = b_pre[d0 + 256], a2 = b_pre[d0 + 512];
    #pragma unroll 8
    for (int s = 0; s < TOPK; ++s) {
        const float v = selVal[s];
        const float* wr = W_dec + (size_t)selIdx[s] * K_DIM;
        a0 = fmaf(v, wr[d0], a0);
        a1 = fmaf(v, wr[d0 + 256], a1);
        a2 = fmaf(v, wr[d0 + 512], a2);
    }
    float* rrow = recon + (size_t)row * K_DIM;
    rrow[d0] = a0;
    rrow[d0 + 256] = a1;
    rrow[d0 + 512] = a2;
}

// ---------------------------------------------------------------------------
extern "C" void kernel_launch(void* const* d_in, const int* in_sizes, int n_in,
                              void* d_out, int out_size, void* d_ws, size_t ws_size,
                              hipStream_t stream) {
    const float* A     = (const float*)d_in[0];
    const float* W_enc = (const float*)d_in[1];
    const float* W_dec = (const float*)d_in[2];
    const float* b_pre = (const float*)d_in[3];

    float* recon = (float*)d_out;
    float* acts  = recon + (size_t)M_ROWS * K_DIM;
    float* zbuf  = acts + (size_t)M_ROWS * N_HID;

    // scratch for bf16-split operands lives in the z region (overwritten by
    // topk_decode at the very end): WT 113.2MB + Acat 18.9MB << 402MB.
    unsigned short* WT   = (unsigned short*)zbuf;
    unsigned short* Acat = WT + (size_t)N_HID * KC;

    convert_a<<<M_ROWS * K_DIM / 4 / 256, 256, 0, stream>>>(A, b_pre, Acat);
    convert_w<<<dim3(N_HID / 64, K_DIM / 64), 256, 0, stream>>>(W_enc, WT);
    encode_mfma<<<dim3(N_HID / 128, M_ROWS / 128), 256, 0, stream>>>(Acat, WT, acts);
    topk_decode<<<M_ROWS, 256, 0, stream>>>(acts, A, W_dec, b_pre, zbuf, recon);
}

// Round 2
// 1670.640 us; speedup vs baseline: 1.9322x; 1.0343x over previous
//
#include <hip/hip_runtime.h>
#include <cstdint>

#define M_ROWS 4096
#define K_DIM  768
#define N_HID  24576
#define TOPK   32
#define MAXCAND 128
#define NBIN   4096

typedef float f32x4 __attribute__((ext_vector_type(4)));
typedef short s16x8 __attribute__((ext_vector_type(8)));

// ---------------------------------------------------------------------------
// bf16 split helpers (hand-rolled RNE; no NaN/Inf in this data)
// ---------------------------------------------------------------------------
__device__ __forceinline__ unsigned short f2bf_rne(float f) {
    uint32_t u = __float_as_uint(f);
    uint32_t r = (u + 0x7fffu + ((u >> 16) & 1u)) >> 16;
    return (unsigned short)r;
}
__device__ __forceinline__ float bf2f(unsigned short h) {
    return __uint_as_float((uint32_t)h << 16);
}

// global -> LDS async copy, 16B per lane, wave-uniform LDS base
#define GLOAD(g, l) __builtin_amdgcn_global_load_lds( \
    (const __attribute__((address_space(1))) uint32_t*)(g), \
    (__attribute__((address_space(3))) uint32_t*)(l), 16, 0, 0)

#define KC 2304   // 3*768: split-K concat [Ah|Ah|Al] x [Wh|Wl|Wh]

// ---------------------------------------------------------------------------
// Kernel 0a: Acat[m, 0:768]=hi(A-b), [768:1536]=hi, [1536:2304]=lo
// ---------------------------------------------------------------------------
__global__ __launch_bounds__(256) void convert_a(
    const float* __restrict__ A, const float* __restrict__ b_pre,
    unsigned short* __restrict__ Acat)
{
    const int idx = blockIdx.x * 256 + threadIdx.x;    // over M*K/4
    const int m  = idx / (K_DIM / 4);
    const int k  = (idx % (K_DIM / 4)) * 4;
    const float4 a4 = *(const float4*)(A + (size_t)m * K_DIM + k);
    const float4 b4 = *(const float4*)(b_pre + k);
    const float av[4] = {a4.x - b4.x, a4.y - b4.y, a4.z - b4.z, a4.w - b4.w};
    unsigned short hi[4], lo[4];
    #pragma unroll
    for (int i = 0; i < 4; ++i) {
        hi[i] = f2bf_rne(av[i]);
        lo[i] = f2bf_rne(av[i] - bf2f(hi[i]));
    }
    unsigned short* row = Acat + (size_t)m * KC + k;
    *(ushort4*)(row)        = make_ushort4(hi[0], hi[1], hi[2], hi[3]);
    *(ushort4*)(row + 768)  = make_ushort4(hi[0], hi[1], hi[2], hi[3]);
    *(ushort4*)(row + 1536) = make_ushort4(lo[0], lo[1], lo[2], lo[3]);
}

// ---------------------------------------------------------------------------
// Kernel 0b: WT[n, 0:768]=hi(W[:,n]), [768:1536]=lo, [1536:2304]=hi  (B^T)
// ---------------------------------------------------------------------------
__global__ __launch_bounds__(256) void convert_w(
    const float* __restrict__ W, unsigned short* __restrict__ WT)
{
    __shared__ float tile[64][65];
    const int tid = threadIdx.x;
    const int n0 = blockIdx.x * 64;
    const int k0 = blockIdx.y * 64;

    #pragma unroll
    for (int i = 0; i < 16; ++i) {
        int e = i * 256 + tid;
        int r = e >> 6, c = e & 63;          // r: k-row, c: n-col
        tile[r][c] = W[(size_t)(k0 + r) * N_HID + n0 + c];
    }
    __syncthreads();
    #pragma unroll
    for (int i = 0; i < 8; ++i) {
        int p = i * 256 + tid;               // 0..2047
        int n = p >> 5;                      // 0..63
        int k2 = (p & 31) * 2;               // 0..62 step 2
        float v0 = tile[k2][n], v1 = tile[k2 + 1][n];
        unsigned short h0 = f2bf_rne(v0), h1 = f2bf_rne(v1);
        unsigned short l0 = f2bf_rne(v0 - bf2f(h0)), l1 = f2bf_rne(v1 - bf2f(h1));
        unsigned short* row = WT + (size_t)(n0 + n) * KC + k0 + k2;
        *(ushort2*)(row)        = make_ushort2(h0, h1);
        *(ushort2*)(row + 768)  = make_ushort2(l0, l1);
        *(ushort2*)(row + 1536) = make_ushort2(h0, h1);
    }
}

// ---------------------------------------------------------------------------
// Kernel 1: acts = Acat @ WT^T   (bf16 MFMA, fp32 accumulate)
// 128x128 tile, BK=32, 4 waves x (64x64), 4x4 frags of 16x16x32. m97 structure.
// ---------------------------------------------------------------------------
__global__ __launch_bounds__(256) void encode_mfma(
    const unsigned short* __restrict__ Acat, const unsigned short* __restrict__ WT,
    float* __restrict__ acts)
{
    __shared__ unsigned short As[128 * 32];
    __shared__ unsigned short Bs[128 * 32];

    const int tid  = threadIdx.x;
    const int lane = tid & 63;
    const int wave = tid >> 6;
    const int wr = wave >> 1;                  // 0..1: wave row
    const int wc = wave & 1;                   // 0..1: wave col
    const int m0 = blockIdx.y * 128;
    const int n0 = blockIdx.x * 128;

    f32x4 acc[4][4] = {};

    const int c0   = wave * 2;
    const int row0 = c0 * 16 + (lane >> 2);
    const int kel  = (lane & 3) * 8;
    const unsigned short* aSrc0 = Acat + (size_t)(m0 + row0) * KC + kel;
    const unsigned short* aSrc1 = aSrc0 + (size_t)16 * KC;
    const unsigned short* bSrc0 = WT   + (size_t)(n0 + row0) * KC + kel;
    const unsigned short* bSrc1 = bSrc0 + (size_t)16 * KC;
    unsigned short* aDst0 = As + c0 * 512;
    unsigned short* aDst1 = As + (c0 + 1) * 512;
    unsigned short* bDst0 = Bs + c0 * 512;
    unsigned short* bDst1 = Bs + (c0 + 1) * 512;

    const int aoff = (wr * 64 + (lane & 15)) * 32 + (lane >> 4) * 8;
    const int boff = (wc * 64 + (lane & 15)) * 32 + (lane >> 4) * 8;

    for (int k0 = 0; k0 < KC; k0 += 32) {
        GLOAD(aSrc0 + k0, aDst0);
        GLOAD(aSrc1 + k0, aDst1);
        GLOAD(bSrc0 + k0, bDst0);
        GLOAD(bSrc1 + k0, bDst1);
        __syncthreads();

        s16x8 a[4], b[4];
        #pragma unroll
        for (int i = 0; i < 4; ++i)
            a[i] = *(const s16x8*)(As + aoff + i * 16 * 32);
        #pragma unroll
        for (int j = 0; j < 4; ++j)
            b[j] = *(const s16x8*)(Bs + boff + j * 16 * 32);
        #pragma unroll
        for (int i = 0; i < 4; ++i)
            #pragma unroll
            for (int j = 0; j < 4; ++j)
                asm("v_mfma_f32_16x16x32_bf16 %0, %1, %2, %0"
                    : "+v"(acc[i][j]) : "v"(a[i]), "v"(b[j]));
        __syncthreads();
    }

    const int crow = (lane >> 4) * 4;
    const int ccol = lane & 15;
    #pragma unroll
    for (int i = 0; i < 4; ++i) {
        #pragma unroll
        for (int r = 0; r < 4; ++r) {
            float* dst = acts + (size_t)(m0 + wr * 64 + i * 16 + crow + r) * N_HID
                       + n0 + wc * 64 + ccol;
            #pragma unroll
            for (int j = 0; j < 4; ++j)
                dst[j * 16] = acc[i][j][r];
        }
    }
}

// ---------------------------------------------------------------------------
// Kernel 2: per-row top-32.  Single-pass 12-bit histogram select (coarse,
// bin-floor threshold) -> candidate superset -> fp64 repair -> z + decode.
// ---------------------------------------------------------------------------
__device__ __forceinline__ uint32_t f2k(float f) {
    uint32_t b = __float_as_uint(f);
    return (b & 0x80000000u) ? ~b : (b | 0x80000000u);
}
__device__ __forceinline__ float k2f(uint32_t k) {
    return __uint_as_float((k & 0x80000000u) ? (k ^ 0x80000000u) : ~k);
}

__global__ __launch_bounds__(256) void topk_decode(
    const float* __restrict__ acts, const float* __restrict__ A,
    const float* __restrict__ W_dec, const float* __restrict__ b_pre,
    float* __restrict__ z, float* __restrict__ recon)
{
    const int row = blockIdx.x;
    const int tid = threadIdx.x;
    const float* arow = acts + (size_t)row * N_HID;

    __shared__ float    ash[K_DIM];       // A[row,:] - b_pre
    __shared__ uint32_t hist[NBIN];       // 16 KB, 12-bit key-prefix bins
    __shared__ uint32_t sfx[256];
    __shared__ uint32_t bsel;
    __shared__ int      candN;
    __shared__ int      candIdx[MAXCAND];
    __shared__ double   candVal[MAXCAND];
    __shared__ double   partsum[2][MAXCAND];
    __shared__ int      selIdx[TOPK];
    __shared__ float    selVal[TOPK];

    for (int i = tid; i < K_DIM; i += 256) ash[i] = A[(size_t)row * K_DIM + i] - b_pre[i];

    // zero histogram + candN
    #pragma unroll
    for (int i = 0; i < NBIN / 256; ++i) hist[tid + i * 256] = 0u;
    if (tid == 0) candN = 0;

    // load row as order-preserving u32 keys in registers
    uint32_t key[96];
    #pragma unroll
    for (int i = 0; i < 24; ++i) {
        const float4 v = *(const float4*)(arow + ((size_t)(tid + i * 256) << 2));
        key[i * 4 + 0] = f2k(v.x);
        key[i * 4 + 1] = f2k(v.y);
        key[i * 4 + 2] = f2k(v.z);
        key[i * 4 + 3] = f2k(v.w);
    }
    __syncthreads();

    // ---- single histogram pass on top 12 key bits ----
    #pragma unroll
    for (int i = 0; i < 96; ++i) atomicAdd(&hist[key[i] >> 20], 1u);
    __syncthreads();

    // ---- suffix scan over 4096 bins: thread t owns bins [16t, 16t+16) ----
    uint32_t loc[16];
    {
        uint32_t run = 0;
        #pragma unroll
        for (int j = 15; j >= 0; --j) { run += hist[tid * 16 + j]; loc[j] = run; }
        sfx[tid] = run;   // total of own 16 bins
    }
    __syncthreads();
    for (int off = 1; off < 256; off <<= 1) {
        uint32_t t = (tid + off < 256) ? sfx[tid + off] : 0u;
        __syncthreads();
        sfx[tid] += t;
        __syncthreads();
    }
    // sfx[t] = count of keys >= (16t)<<20
    {
        const uint32_t S_before = (tid < 255) ? sfx[tid + 1] : 0u;
        uint32_t Sb1 = S_before;              // S(bin+1)
        #pragma unroll
        for (int j = 15; j >= 0; --j) {
            uint32_t Sb = S_before + loc[j];  // S(bin)
            if (Sb >= TOPK && Sb1 < TOPK) bsel = (uint32_t)(tid * 16 + j);
            Sb1 = Sb;
        }
    }
    __syncthreads();

    // bin-floor threshold minus fp32-error band -> candidate superset.
    // bin width at typical threshold (~0.75) is 0.0625 -> ~27 in-bin values;
    // candidates <= 31 + binpop + band (~60 typical), MAXCAND=128 is >10 sigma.
    const float vT = k2f(bsel << 20);
    const uint32_t keyLo = f2k(vT - 1e-3f);

    #pragma unroll
    for (int i = 0; i < 24; ++i) {
        #pragma unroll
        for (int j = 0; j < 4; ++j) {
            if (key[i * 4 + j] >= keyLo) {
                int s = atomicAdd(&candN, 1);
                if (s < MAXCAND) candIdx[s] = (tid + i * 256) * 4 + j;
            }
        }
    }
    __syncthreads();
    const int nc = candN < MAXCAND ? candN : MAXCAND;

    // ---- fp64 recompute of candidates: dot(ash, W_dec[idx,:]) ----
    {
        const int c = tid & 127, part = tid >> 7;   // 2 parts x 384 elems
        double s0 = 0.0, s1 = 0.0;
        if (c < nc) {
            const float* wr = W_dec + (size_t)candIdx[c] * K_DIM + part * 384;
            const float* ar = ash + part * 384;
            #pragma unroll 4
            for (int d = 0; d < 384; d += 2) {
                s0 += (double)ar[d]     * (double)wr[d];
                s1 += (double)ar[d + 1] * (double)wr[d + 1];
            }
        }
        partsum[part][c] = s0 + s1;
    }
    __syncthreads();
    if (tid < MAXCAND)
        candVal[tid] = partsum[0][tid] + partsum[1][tid];
    __syncthreads();

    // ---- rank candidates by (fp64 value desc, index asc); take top 32 ----
    if (tid < nc) {
        const double v = candVal[tid];
        const int    idx = candIdx[tid];
        int rank = 0;
        for (int t = 0; t < nc; ++t) {
            double vt2 = candVal[t]; int it = candIdx[t];
            if (vt2 > v || (vt2 == v && it < idx)) rank++;
        }
        if (rank < TOPK) { selIdx[rank] = idx; selVal[rank] = (float)v; }
    }
    __syncthreads();

    // ---- z row: dense zeros, then scatter the 32 selected ----
    float* zrow = z + (size_t)row * N_HID;
    const float4 zero4 = make_float4(0.f, 0.f, 0.f, 0.f);
    #pragma unroll
    for (int i = 0; i < 24; ++i)
        *(float4*)(zrow + ((size_t)(tid + i * 256) << 2)) = zero4;
    __syncthreads();
    if (tid < TOPK) zrow[selIdx[tid]] = selVal[tid];

    // ---- fused decode: recon[row,:] = sum_s val_s * W_dec[idx_s,:] + b_pre ----
    const int d0 = tid;
    float a0 = b_pre[d0], a1 = b_pre[d0 + 256], a2 = b_pre[d0 + 512];
    #pragma unroll 8
    for (int s = 0; s < TOPK; ++s) {
        const float v = selVal[s];
        const float* wr = W_dec + (size_t)selIdx[s] * K_DIM;
        a0 = fmaf(v, wr[d0], a0);
        a1 = fmaf(v, wr[d0 + 256], a1);
        a2 = fmaf(v, wr[d0 + 512], a2);
    }
    float* rrow = recon + (size_t)row * K_DIM;
    rrow[d0] = a0;
    rrow[d0 + 256] = a1;
    rrow[d0 + 512] = a2;
}

// ---------------------------------------------------------------------------
extern "C" void kernel_launch(void* const* d_in, const int* in_sizes, int n_in,
                              void* d_out, int out_size, void* d_ws, size_t ws_size,
                              hipStream_t stream) {
    const float* A     = (const float*)d_in[0];
    const float* W_enc = (const float*)d_in[1];
    const float* W_dec = (const float*)d_in[2];
    const float* b_pre = (const float*)d_in[3];

    float* recon = (float*)d_out;
    float* acts  = recon + (size_t)M_ROWS * K_DIM;
    float* zbuf  = acts + (size_t)M_ROWS * N_HID;

    // scratch for bf16-split operands lives in the z region (overwritten by
    // topk_decode at the very end): WT 113.2MB + Acat 18.9MB << 402MB.
    unsigned short* WT   = (unsigned short*)zbuf;
    unsigned short* Acat = WT + (size_t)N_HID * KC;

    convert_a<<<M_ROWS * K_DIM / 4 / 256, 256, 0, stream>>>(A, b_pre, Acat);
    convert_w<<<dim3(N_HID / 64, K_DIM / 64), 256, 0, stream>>>(W_enc, WT);
    encode_mfma<<<dim3(N_HID / 128, M_ROWS / 128), 256, 0, stream>>>(Acat, WT, acts);
    topk_decode<<<M_ROWS, 256, 0, stream>>>(acts, A, W_dec, b_pre, zbuf, recon);
}